// Round 9
// baseline (642.676 us; speedup 1.0000x reference)
//
#include <hip/hip_runtime.h>
#include <hip/hip_bf16.h>

// ---------------------------------------------------------------------------
// GAT x3 + fc + MLP. R9: R8 (best, 538us) + MLP branch co-scheduled into the
// GAT-path dispatches via block-range dispatch (no extra streams needed; the
// kernel-boundary ordering gives MLP1 -> MLP2 -> MLP3):
//   gemm_gat L0  (+MLP1: t1 = rc @ rW1)
//   gat_agg  L0  (+MLP2: t2 = t1 @ rW2)
//   gemm_gat L1  (+MLP3: outRoot = t2 @ rW3)
// Host kernels saturate neither VALU nor HBM, so the appended GEMM blocks
// hide under them. Everything else unchanged from R8.
// ---------------------------------------------------------------------------

#define GAT_SLOPE 0.2f
#define ACT_SLOPE 0.01f

typedef unsigned short ushort_t;
typedef __attribute__((ext_vector_type(8))) short bf16x8;
typedef __attribute__((ext_vector_type(4))) unsigned short ushort4v;
typedef __attribute__((ext_vector_type(4))) float floatx4;

__device__ __forceinline__ float lrelu(float x, float s) {
    return fmaxf(x, s * x);   // valid for 0<s<1
}

__device__ __forceinline__ ushort_t f2bf(float f) {
    union { float f; unsigned u; } x; x.f = f;
    unsigned r = x.u + 0x7FFF + ((x.u >> 16) & 1);   // round-nearest-even
    return (ushort_t)(r >> 16);
}

__device__ __forceinline__ float bf2f(ushort_t u) {
    union { unsigned u; float f; } x; x.u = ((unsigned)u) << 16;
    return x.f;
}

// async 16B global->LDS; lds base must be wave-uniform (HW adds lane*16)
__device__ __forceinline__ void gl_lds16(const ushort_t* g, ushort_t* l) {
    __builtin_amdgcn_global_load_lds(
        (const __attribute__((address_space(1))) unsigned int*)g,
        (__attribute__((address_space(3))) unsigned int*)l, 16, 0, 0);
}

// ---------------- shared staged-GEMM tile body (A,Bt bf16; 128x128 tile) ----
// As/Bs: [128*32] LDS. K multiple of 32, operands zero-padded.
__device__ __forceinline__ void gemm_tile(
    const ushort_t* __restrict__ A, const ushort_t* __restrict__ Bt,
    const float* __restrict__ bias, void* __restrict__ Cout,
    int Ncols, int K, int act, float slope, int outBf,
    int rowBase, int colBase, ushort_t* As, ushort_t* Bs, int t) {
    int wave = t >> 6, lane = t & 63;
    int wm = (wave >> 1) << 6;
    int wn = (wave & 1) << 6;
    int lrow = lane & 15, lquad = lane >> 4;
    floatx4 acc[4][4];
#pragma unroll
    for (int i = 0; i < 4; i++)
#pragma unroll
        for (int j = 0; j < 4; j++) acc[i][j] = (floatx4){0.f, 0.f, 0.f, 0.f};

    int c0 = wave * 64 + lane;
    const ushort_t* gA0 = A + (size_t)(rowBase + (c0 >> 2)) * K + ((c0 & 3) << 3);
    const ushort_t* gB0 = Bt + (size_t)(colBase + (c0 >> 2)) * K + ((c0 & 3) << 3);
    int c1 = 256 + c0;
    const ushort_t* gA1 = A + (size_t)(rowBase + (c1 >> 2)) * K + ((c1 & 3) << 3);
    const ushort_t* gB1 = Bt + (size_t)(colBase + (c1 >> 2)) * K + ((c1 & 3) << 3);
    ushort_t* lA0 = As + (size_t)(wave * 64) * 8;
    ushort_t* lB0 = Bs + (size_t)(wave * 64) * 8;
    ushort_t* lA1 = As + (size_t)(256 + wave * 64) * 8;
    ushort_t* lB1 = Bs + (size_t)(256 + wave * 64) * 8;

    for (int k0 = 0; k0 < K; k0 += 32) {
        gl_lds16(gA0 + k0, lA0);
        gl_lds16(gA1 + k0, lA1);
        gl_lds16(gB0 + k0, lB0);
        gl_lds16(gB1 + k0, lB1);
        __syncthreads();
        bf16x8 af[4], bfv[4];
#pragma unroll
        for (int i = 0; i < 4; i++)
            af[i] = *(const bf16x8*)(As + (wm + i * 16 + lrow) * 32 + lquad * 8);
#pragma unroll
        for (int j = 0; j < 4; j++)
            bfv[j] = *(const bf16x8*)(Bs + (wn + j * 16 + lrow) * 32 + lquad * 8);
#pragma unroll
        for (int i = 0; i < 4; i++)
#pragma unroll
            for (int j = 0; j < 4; j++)
                acc[i][j] = __builtin_amdgcn_mfma_f32_16x16x32_bf16(af[i], bfv[j],
                                                                    acc[i][j], 0, 0, 0);
        __syncthreads();
    }
#pragma unroll
    for (int i = 0; i < 4; i++) {
        int gr = rowBase + wm + i * 16 + lquad * 4;
#pragma unroll
        for (int j = 0; j < 4; j++) {
            int gc = colBase + wn + j * 16 + lrow;
            if (gc >= Ncols) continue;
            float b = bias ? bias[gc] : 0.f;
#pragma unroll
            for (int r = 0; r < 4; r++) {
                float v = acc[i][j][r] + b;
                if (act) v = lrelu(v, slope);
                if (outBf)
                    ((ushort_t*)Cout)[(size_t)(gr + r) * Ncols + gc] = f2bf(v);
                else
                    ((float*)Cout)[(size_t)(gr + r) * Ncols + gc] = v;
            }
        }
    }
}

// ---------------- edge-index format probe ----------------
__global__ void detect_fmt(const int* __restrict__ raw, int nwords, int* flag) {
    __shared__ int nz;
    if (threadIdx.x == 0) nz = 0;
    __syncthreads();
    int lim = nwords < 4096 ? nwords : 4096;
    for (int i = threadIdx.x * 2 + 1; i < lim; i += 512)
        if (raw[i] != 0) atomicAdd(&nz, 1);
    __syncthreads();
    if (threadIdx.x == 0) *flag = (nz == 0) ? 1 : 0;   // 1 => int64 storage
}

__global__ void zero2(int* __restrict__ a, int* __restrict__ b, int n) {
    int i = blockIdx.x * blockDim.x + threadIdx.x;
    if (i < n) { a[i] = 0; b[i] = 0; }
}

__global__ void convert_count(const int* __restrict__ raw, int E,
                              const int* __restrict__ flag,
                              int* __restrict__ idx32, int* __restrict__ counts) {
    int i = blockIdx.x * blockDim.x + threadIdx.x;
    if (i >= E) return;
    int f = *flag;
    int s = f ? raw[2 * i] : raw[i];
    int d = f ? raw[2 * (E + i)] : raw[E + i];
    idx32[i] = s;
    idx32[E + i] = d;
    atomicAdd(&counts[d], 1);
}

__global__ void scan_block(const int* __restrict__ counts, int* __restrict__ inc,
                           int* __restrict__ blockSums, int N) {
    __shared__ int sh[256];
    int i = blockIdx.x * 256 + threadIdx.x;
    int v = (i < N) ? counts[i] : 0;
    sh[threadIdx.x] = v;
    __syncthreads();
    for (int off = 1; off < 256; off <<= 1) {
        int t = (threadIdx.x >= off) ? sh[threadIdx.x - off] : 0;
        __syncthreads();
        sh[threadIdx.x] += t;
        __syncthreads();
    }
    if (i < N) inc[i] = sh[threadIdx.x];
    if (threadIdx.x == 255) blockSums[blockIdx.x] = sh[255];
}

__global__ void scan_sums(int* __restrict__ blockSums, int nb, int* __restrict__ row_ptr) {
    __shared__ int sh[512];
    int v = ((int)threadIdx.x < nb) ? blockSums[threadIdx.x] : 0;
    sh[threadIdx.x] = v;
    __syncthreads();
    for (int off = 1; off < 512; off <<= 1) {
        int t = (threadIdx.x >= off) ? sh[threadIdx.x - off] : 0;
        __syncthreads();
        sh[threadIdx.x] += t;
        __syncthreads();
    }
    if ((int)threadIdx.x < nb) blockSums[threadIdx.x] = sh[threadIdx.x];
    if (threadIdx.x == 0) row_ptr[0] = 0;
}

__global__ void scan_add(const int* __restrict__ inc, const int* __restrict__ blockSums,
                         int* __restrict__ row_ptr, int N) {
    int i = blockIdx.x * 256 + threadIdx.x;
    if (i < N) row_ptr[i + 1] = inc[i] + (blockIdx.x > 0 ? blockSums[blockIdx.x - 1] : 0);
}

__global__ void edge_fill(const int* __restrict__ src, const int* __restrict__ dst, int E,
                          const int* __restrict__ row_ptr, int* __restrict__ cursor,
                          int* __restrict__ col) {
    int i = blockIdx.x * blockDim.x + threadIdx.x;
    if (i < E) {
        int d = dst[i];
        int pos = row_ptr[d] + atomicAdd(&cursor[d], 1);
        col[pos] = src[i];
    }
}

// ---------------- conversions ----------------
__global__ void convert_padrow(const float* __restrict__ in, ushort_t* __restrict__ out,
                               int M, int Kr, int Kp) {
    int i = blockIdx.x * blockDim.x + threadIdx.x;
    if (i >= M * Kp) return;
    int r = i / Kp, c = i - r * Kp;
    out[i] = f2bf((c < Kr) ? in[(size_t)r * Kr + c] : 0.f);
}

struct WConv { const float* in; ushort_t* out; int Kp, Kr, N, Npad, blkOff; };
struct WConvArr { WConv e[7]; int n; };

__global__ void convert_w_multi(WConvArr a) {
    int b = blockIdx.x;
    int ei = 0;
    for (int k = 1; k < a.n; k++)
        if (b >= a.e[k].blkOff) ei = k;
    WConv w = a.e[ei];
    int i = (b - w.blkOff) * 256 + threadIdx.x;
    if (i >= w.Npad * w.Kp) return;
    int n = i / w.Kp, k = i - n * w.Kp;
    float v = (n < w.N && k < w.Kr) ? w.in[(size_t)k * w.N + n] : 0.f;
    w.out[i] = f2bf(v);
}

// ---------------- staged GAT GEMM (+ optional piggy-backed MLP GEMM) --------
// Main: grid.y < gatY -> GAT tile. Extra rows -> MLP GEMM blocks.
__global__ __launch_bounds__(256) void gemm_gat(
    const ushort_t* __restrict__ A, const ushort_t* __restrict__ Bt,
    const float* __restrict__ a_src, const float* __restrict__ a_dst,
    ushort_t* __restrict__ Hbf, float* __restrict__ al_s, float* __restrict__ al_d,
    int M, int K, int gatY,
    const ushort_t* __restrict__ mA, const ushort_t* __restrict__ mBt,
    const float* __restrict__ mBias, void* __restrict__ mOut,
    int mN, int mK, int mAct, int mOutBf, int mColTiles) {
    __shared__ __align__(16) ushort_t As[128 * 32];
    __shared__ __align__(16) ushort_t Bs[128 * 32];
    int t = threadIdx.x;

    if ((int)blockIdx.y >= gatY) {
        int lid = ((int)blockIdx.y - gatY) * 2 + (int)blockIdx.x;
        int rowTile = lid / mColTiles, colTile = lid - rowTile * mColTiles;
        gemm_tile(mA, mBt, mBias, mOut, mN, mK, mAct, ACT_SLOPE, mOutBf,
                  rowTile << 7, colTile << 7, As, Bs, t);
        return;
    }

    int wave = t >> 6, lane = t & 63;
    int wm = (wave >> 1) << 6;
    int wn = (wave & 1) << 6;
    int rowBase = blockIdx.y << 7;
    int colBase = blockIdx.x << 7;
    int lrow = lane & 15, lquad = lane >> 4;
    floatx4 acc[4][4];
#pragma unroll
    for (int i = 0; i < 4; i++)
#pragma unroll
        for (int j = 0; j < 4; j++) acc[i][j] = (floatx4){0.f, 0.f, 0.f, 0.f};

    int c0 = wave * 64 + lane;
    const ushort_t* gA0 = A + (size_t)(rowBase + (c0 >> 2)) * K + ((c0 & 3) << 3);
    const ushort_t* gB0 = Bt + (size_t)(colBase + (c0 >> 2)) * K + ((c0 & 3) << 3);
    int c1 = 256 + c0;
    const ushort_t* gA1 = A + (size_t)(rowBase + (c1 >> 2)) * K + ((c1 & 3) << 3);
    const ushort_t* gB1 = Bt + (size_t)(colBase + (c1 >> 2)) * K + ((c1 & 3) << 3);
    ushort_t* lA0 = As + (size_t)(wave * 64) * 8;
    ushort_t* lB0 = Bs + (size_t)(wave * 64) * 8;
    ushort_t* lA1 = As + (size_t)(256 + wave * 64) * 8;
    ushort_t* lB1 = Bs + (size_t)(256 + wave * 64) * 8;

    for (int k0 = 0; k0 < K; k0 += 32) {
        gl_lds16(gA0 + k0, lA0);
        gl_lds16(gA1 + k0, lA1);
        gl_lds16(gB0 + k0, lB0);
        gl_lds16(gB1 + k0, lB1);
        __syncthreads();
        bf16x8 af[4], bfv[4];
#pragma unroll
        for (int i = 0; i < 4; i++)
            af[i] = *(const bf16x8*)(As + (wm + i * 16 + lrow) * 32 + lquad * 8);
#pragma unroll
        for (int j = 0; j < 4; j++)
            bfv[j] = *(const bf16x8*)(Bs + (wn + j * 16 + lrow) * 32 + lquad * 8);
#pragma unroll
        for (int i = 0; i < 4; i++)
#pragma unroll
            for (int j = 0; j < 4; j++)
                acc[i][j] = __builtin_amdgcn_mfma_f32_16x16x32_bf16(af[i], bfv[j],
                                                                    acc[i][j], 0, 0, 0);
        __syncthreads();
    }
    // epilogue: al_s/al_d per (row, head) + bf16 h store (NCOL=256)
    int head = (colBase + wn) >> 6;
    float avs[4], avd[4];
#pragma unroll
    for (int j = 0; j < 4; j++) {
        avs[j] = a_src[head * 64 + j * 16 + lrow];
        avd[j] = a_dst[head * 64 + j * 16 + lrow];
    }
#pragma unroll
    for (int i = 0; i < 4; i++) {
#pragma unroll
        for (int r = 0; r < 4; r++) {
            float ps = 0.f, pd = 0.f;
#pragma unroll
            for (int j = 0; j < 4; j++) {
                ps += acc[i][j][r] * avs[j];
                pd += acc[i][j][r] * avd[j];
            }
#pragma unroll
            for (int off = 1; off < 16; off <<= 1) {
                ps += __shfl_xor(ps, off);
                pd += __shfl_xor(pd, off);
            }
            if (lrow == 0) {
                int gr = rowBase + wm + i * 16 + lquad * 4 + r;
                al_s[gr * 4 + head] = ps;
                al_d[gr * 4 + head] = pd;
            }
        }
        int grb = rowBase + wm + i * 16 + lquad * 4;
#pragma unroll
        for (int j = 0; j < 4; j++) {
            int gc = colBase + wn + j * 16 + lrow;
#pragma unroll
            for (int r = 0; r < 4; r++)
                Hbf[(size_t)(grb + r) * 256 + gc] = f2bf(acc[i][j][r]);
        }
    }
}

// ---------------- standalone staged GEMM (fc) ----------------
__global__ __launch_bounds__(256) void gemm_plain(
    const ushort_t* __restrict__ A, const ushort_t* __restrict__ Bt,
    const float* __restrict__ bias, void* __restrict__ Cout,
    int M, int N, int K, int act, float slope, int outBf) {
    __shared__ __align__(16) ushort_t As[128 * 32];
    __shared__ __align__(16) ushort_t Bs[128 * 32];
    gemm_tile(A, Bt, bias, Cout, N, K, act, slope, outBf,
              (int)(blockIdx.y << 7), (int)(blockIdx.x << 7), As, Bs,
              (int)threadIdx.x);
}

// ---------------- aggregation (+ piggy-backed MLP GEMM blocks) --------------
__global__ __launch_bounds__(256) void gat_agg(
    const ushort_t* __restrict__ h_bf, const float* __restrict__ al_s,
    const float* __restrict__ al_d, const int* __restrict__ row_ptr,
    const int* __restrict__ col, const float* __restrict__ bias,
    ushort_t* __restrict__ out_bf, int N, int act, float slope, int aggBlocks,
    const ushort_t* __restrict__ mA, const ushort_t* __restrict__ mBt,
    const float* __restrict__ mBias, void* __restrict__ mOut,
    int mN, int mK, int mAct, int mOutBf, int mColTiles) {
    if ((int)blockIdx.x >= aggBlocks) {
        __shared__ __align__(16) ushort_t As[128 * 32];
        __shared__ __align__(16) ushort_t Bs[128 * 32];
        int lid = (int)blockIdx.x - aggBlocks;
        int rowTile = lid / mColTiles, colTile = lid - rowTile * mColTiles;
        gemm_tile(mA, mBt, mBias, mOut, mN, mK, mAct, ACT_SLOPE, mOutBf,
                  rowTile << 7, colTile << 7, As, Bs, (int)threadIdx.x);
        return;
    }
    int gw = __builtin_amdgcn_readfirstlane((blockIdx.x * 256 + threadIdx.x) >> 6);
    if (gw >= N) return;
    int lane = threadIdx.x & 63;
    int head = lane >> 4;
    int idx = gw * 4 + head;
    float ad = al_d[idx];
    const ushort4v* h4 = (const ushort4v*)h_bf;
    // self loop
    float p = __expf(lrelu(al_s[idx] + ad, GAT_SLOPE));
    ushort4v hv = h4[(size_t)gw * 64 + lane];
    float s = p;
    float4 acc;
    acc.x = p * bf2f(hv.x); acc.y = p * bf2f(hv.y);
    acc.z = p * bf2f(hv.z); acc.w = p * bf2f(hv.w);
    int beg = row_ptr[gw], end = row_ptr[gw + 1];
    for (int i = beg; i < end; i += 4) {
        int cnt = end - i;                 // wave-uniform
        int sn0 = col[i];
        int sn1 = (cnt > 1) ? col[i + 1] : sn0;
        int sn2 = (cnt > 2) ? col[i + 2] : sn0;
        int sn3 = (cnt > 3) ? col[i + 3] : sn0;
        ushort4v h0 = h4[(size_t)sn0 * 64 + lane];
        ushort4v h1 = h4[(size_t)sn1 * 64 + lane];
        ushort4v h2 = h4[(size_t)sn2 * 64 + lane];
        ushort4v h3 = h4[(size_t)sn3 * 64 + lane];
        float a0 = al_s[sn0 * 4 + head];
        float a1 = al_s[sn1 * 4 + head];
        float a2 = al_s[sn2 * 4 + head];
        float a3 = al_s[sn3 * 4 + head];
        float p0 = __expf(lrelu(a0 + ad, GAT_SLOPE));
        acc.x += p0 * bf2f(h0.x); acc.y += p0 * bf2f(h0.y);
        acc.z += p0 * bf2f(h0.z); acc.w += p0 * bf2f(h0.w);
        s += p0;
        if (cnt > 1) {
            float p1 = __expf(lrelu(a1 + ad, GAT_SLOPE));
            acc.x += p1 * bf2f(h1.x); acc.y += p1 * bf2f(h1.y);
            acc.z += p1 * bf2f(h1.z); acc.w += p1 * bf2f(h1.w);
            s += p1;
        }
        if (cnt > 2) {
            float p2 = __expf(lrelu(a2 + ad, GAT_SLOPE));
            acc.x += p2 * bf2f(h2.x); acc.y += p2 * bf2f(h2.y);
            acc.z += p2 * bf2f(h2.z); acc.w += p2 * bf2f(h2.w);
            s += p2;
        }
        if (cnt > 3) {
            float p3 = __expf(lrelu(a3 + ad, GAT_SLOPE));
            acc.x += p3 * bf2f(h3.x); acc.y += p3 * bf2f(h3.y);
            acc.z += p3 * bf2f(h3.z); acc.w += p3 * bf2f(h3.w);
            s += p3;
        }
    }
    float rs = 1.f / s;
    float4 bv = ((const float4*)bias)[lane];
    acc.x = acc.x * rs + bv.x; acc.y = acc.y * rs + bv.y;
    acc.z = acc.z * rs + bv.z; acc.w = acc.w * rs + bv.w;
    if (act) {
        acc.x = lrelu(acc.x, slope); acc.y = lrelu(acc.y, slope);
        acc.z = lrelu(acc.z, slope); acc.w = lrelu(acc.w, slope);
    }
    ushort4v o;
    o.x = f2bf(acc.x); o.y = f2bf(acc.y); o.z = f2bf(acc.z); o.w = f2bf(acc.w);
    ((ushort4v*)out_bf)[(size_t)gw * 64 + lane] = o;
}

// ---------------------------------------------------------------------------
extern "C" void kernel_launch(void* const* d_in, const int* in_sizes, int n_in,
                              void* d_out, int out_size, void* d_ws, size_t ws_size,
                              hipStream_t stream) {
    const float* x        = (const float*)d_in[0];
    const int*   rawEdge  = (const int*)d_in[1];
    const float* rootCtx  = (const float*)d_in[2];
    const float* W[3]     = {(const float*)d_in[3], (const float*)d_in[7], (const float*)d_in[11]};
    const float* aS[3]    = {(const float*)d_in[4], (const float*)d_in[8], (const float*)d_in[12]};
    const float* aD[3]    = {(const float*)d_in[5], (const float*)d_in[9], (const float*)d_in[13]};
    const float* bb[3]    = {(const float*)d_in[6], (const float*)d_in[10], (const float*)d_in[14]};
    const float* fc_w     = (const float*)d_in[15];
    const float* fc_b     = (const float*)d_in[16];
    const float* r_w1     = (const float*)d_in[17];
    const float* r_b1     = (const float*)d_in[18];
    const float* r_w2     = (const float*)d_in[19];
    const float* r_b2     = (const float*)d_in[20];
    const float* r_w3     = (const float*)d_in[21];
    const float* r_b3     = (const float*)d_in[22];

    const int N  = in_sizes[0] / 80;      // 102400
    const int E  = in_sizes[1] / 2;       // 409600
    const int R  = in_sizes[2] / 60;      // 4096
    const int N4 = N * 4;

    float* outRot  = (float*)d_out;                  // [N, 80]
    float* outRoot = (float*)d_out + (size_t)N * 80; // [R, 60]

    // ---- carve workspace ----
    size_t off = 0;
    auto carve = [&](size_t bytes) -> void* {
        off = (off + 255) & ~(size_t)255;
        void* p = (char*)d_ws + off;
        off += bytes;
        return p;
    };
    int*      flag      = (int*)carve(4);
    int*      idx32     = (int*)carve((size_t)2 * E * 4);
    int*      counts    = (int*)carve((size_t)N * 4);
    int*      cursor    = (int*)carve((size_t)N * 4);
    int*      row_ptr   = (int*)carve((size_t)(N + 1) * 4);
    int*      incArr    = (int*)carve((size_t)N * 4);
    int*      blockSums = (int*)carve(512 * 4);
    int*      colArr    = (int*)carve((size_t)E * 4);
    float*    al_s      = (float*)carve((size_t)N4 * 4);
    float*    al_d      = (float*)carve((size_t)N4 * 4);
    ushort_t* h_bf      = (ushort_t*)carve((size_t)N * 256 * 2);
    ushort_t* agg_bf    = (ushort_t*)carve((size_t)N * 256 * 2);
    ushort_t* x_bf      = (ushort_t*)carve((size_t)N * 96 * 2);    // Kp=96
    ushort_t* rc_bf     = (ushort_t*)carve((size_t)R * 64 * 2);
    ushort_t* t1_bf     = (ushort_t*)carve((size_t)R * 512 * 2);
    ushort_t* t2_bf     = (ushort_t*)carve((size_t)R * 512 * 2);
    ushort_t* Wt0       = (ushort_t*)carve((size_t)256 * 96 * 2);  // Kp=96
    ushort_t* Wt1       = (ushort_t*)carve((size_t)256 * 256 * 2);
    ushort_t* Wt2       = (ushort_t*)carve((size_t)256 * 256 * 2);
    ushort_t* fcWt      = (ushort_t*)carve((size_t)128 * 256 * 2);
    ushort_t* rW1t      = (ushort_t*)carve((size_t)512 * 64 * 2);
    ushort_t* rWt2      = (ushort_t*)carve((size_t)512 * 512 * 2);
    ushort_t* rWt3      = (ushort_t*)carve((size_t)128 * 512 * 2);

    const int nb = (N + 255) / 256;
    dim3 blk(256);

    // ---- edge format + CSR build ----
    detect_fmt<<<1, 256, 0, stream>>>(rawEdge, 2 * E, flag);
    zero2<<<(N + 255) / 256, blk, 0, stream>>>(counts, cursor, N);
    convert_count<<<(E + 255) / 256, blk, 0, stream>>>(rawEdge, E, flag, idx32, counts);
    const int* srcArr = idx32;
    const int* dstArr = idx32 + E;
    scan_block<<<nb, 256, 0, stream>>>(counts, incArr, blockSums, N);
    scan_sums<<<1, 512, 0, stream>>>(blockSums, nb, row_ptr);
    scan_add<<<nb, 256, 0, stream>>>(incArr, blockSums, row_ptr, N);
    edge_fill<<<(E + 255) / 256, blk, 0, stream>>>(srcArr, dstArr, E, row_ptr, cursor, colArr);

    // ---- weight conversions (merged) ----
    {
        WConvArr wa;
        auto mk = [&](int i, const float* in, ushort_t* out, int Kp, int Kr, int Nn, int Npad,
                      int blkOff) {
            wa.e[i] = WConv{in, out, Kp, Kr, Nn, Npad, blkOff};
        };
        int boff = 0;
        auto nblk = [](int Npad, int Kp) { return (Npad * Kp + 255) / 256; };
        mk(0, W[0], Wt0, 96, 80, 256, 256, boff);   boff += nblk(256, 96);
        mk(1, W[1], Wt1, 256, 256, 256, 256, boff); boff += nblk(256, 256);
        mk(2, W[2], Wt2, 256, 256, 256, 256, boff); boff += nblk(256, 256);
        mk(3, fc_w, fcWt, 256, 256, 80, 128, boff); boff += nblk(128, 256);
        mk(4, r_w1, rW1t, 64, 60, 512, 512, boff);  boff += nblk(512, 64);
        mk(5, r_w2, rWt2, 512, 512, 512, 512, boff); boff += nblk(512, 512);
        mk(6, r_w3, rWt3, 512, 512, 60, 128, boff);  boff += nblk(128, 512);
        wa.n = 7;
        convert_w_multi<<<boff, blk, 0, stream>>>(wa);
    }
    convert_padrow<<<(N * 96 + 255) / 256, blk, 0, stream>>>(x, x_bf, N, 80, 96);
    convert_padrow<<<(R * 64 + 255) / 256, blk, 0, stream>>>(rootCtx, rc_bf, R, 60, 64);

    const int gatY = N / 128;            // 800
    const int aggBlocks = (N * 64) / 256; // 25600

    // ---- GAT L0 + MLP1 (t1 = rc @ rW1, 128 blocks -> 64 extra y rows) ----
    {
        dim3 g(2, gatY + 64);
        gemm_gat<<<g, blk, 0, stream>>>(x_bf, Wt0, aS[0], aD[0], h_bf, al_s, al_d,
                                        N, 96, gatY,
                                        rc_bf, rW1t, r_b1, t1_bf, 512, 64, 1, 1, 4);
    }
    // ---- agg L0 + MLP2 (t2 = t1 @ rW2, 128 extra blocks) ----
    gat_agg<<<aggBlocks + 128, blk, 0, stream>>>(h_bf, al_s, al_d, row_ptr, colArr,
                                                 bb[0], agg_bf, N, 1, ACT_SLOPE,
                                                 aggBlocks,
                                                 t1_bf, rWt2, r_b2, t2_bf,
                                                 512, 512, 1, 1, 4);
    // ---- GAT L1 + MLP3 (outRoot = t2 @ rW3, 32 blocks -> 16 extra y rows) --
    {
        dim3 g(2, gatY + 16);
        gemm_gat<<<g, blk, 0, stream>>>(agg_bf, Wt1, aS[1], aD[1], h_bf, al_s, al_d,
                                        N, 256, gatY,
                                        t2_bf, rWt3, r_b3, outRoot, 60, 512, 0, 0, 1);
    }
    gat_agg<<<aggBlocks, blk, 0, stream>>>(h_bf, al_s, al_d, row_ptr, colArr,
                                           bb[1], agg_bf, N, 1, ACT_SLOPE,
                                           aggBlocks,
                                           nullptr, nullptr, nullptr, nullptr,
                                           256, 32, 0, 0, 1);
    // ---- GAT L2 (no piggyback) ----
    {
        dim3 g(2, gatY);
        gemm_gat<<<g, blk, 0, stream>>>(agg_bf, Wt2, aS[2], aD[2], h_bf, al_s, al_d,
                                        N, 256, gatY,
                                        nullptr, nullptr, nullptr, nullptr,
                                        256, 32, 0, 0, 1);
    }
    gat_agg<<<aggBlocks, blk, 0, stream>>>(h_bf, al_s, al_d, row_ptr, colArr,
                                           bb[2], agg_bf, N, 0, ACT_SLOPE,
                                           aggBlocks,
                                           nullptr, nullptr, nullptr, nullptr,
                                           256, 32, 0, 0, 1);
    // ---- rot = h @ fc_w + fc_b ----
    {
        dim3 g(1, N / 128);
        gemm_plain<<<g, blk, 0, stream>>>(agg_bf, fcWt, fc_b, outRot, N, 80, 256,
                                          0, 0.f, 0);
    }
}

// Round 10
// 521.736 us; speedup vs baseline: 1.2318x; 1.2318x over previous
//
#include <hip/hip_runtime.h>
#include <hip/hip_bf16.h>

// ---------------------------------------------------------------------------
// GAT x3 + fc + MLP. R10: exact R8 pipeline (best known, 538us) with gat_agg
// reworked to TWO nodes per wave (lanes 0-31 node A, 32-63 node B; 16B/lane
// ushort8 loads). Halves per-edge wave-instructions, doubles rows in flight.
// R9's piggybacking reverted (resource contamination collapsed occupancy).
// ---------------------------------------------------------------------------

#define GAT_SLOPE 0.2f
#define ACT_SLOPE 0.01f

typedef unsigned short ushort_t;
typedef __attribute__((ext_vector_type(8))) short bf16x8;
typedef __attribute__((ext_vector_type(8))) unsigned short ushort8v;
typedef __attribute__((ext_vector_type(4))) unsigned short ushort4v;
typedef __attribute__((ext_vector_type(4))) float floatx4;

__device__ __forceinline__ float lrelu(float x, float s) {
    return fmaxf(x, s * x);   // valid for 0<s<1
}

__device__ __forceinline__ ushort_t f2bf(float f) {
    union { float f; unsigned u; } x; x.f = f;
    unsigned r = x.u + 0x7FFF + ((x.u >> 16) & 1);   // round-nearest-even
    return (ushort_t)(r >> 16);
}

__device__ __forceinline__ float bf2f(ushort_t u) {
    union { unsigned u; float f; } x; x.u = ((unsigned)u) << 16;
    return x.f;
}

// async 16B global->LDS; lds base must be wave-uniform (HW adds lane*16)
__device__ __forceinline__ void gl_lds16(const ushort_t* g, ushort_t* l) {
    __builtin_amdgcn_global_load_lds(
        (const __attribute__((address_space(1))) unsigned int*)g,
        (__attribute__((address_space(3))) unsigned int*)l, 16, 0, 0);
}

// ---------------- edge-index format probe ----------------
__global__ void detect_fmt(const int* __restrict__ raw, int nwords, int* flag) {
    __shared__ int nz;
    if (threadIdx.x == 0) nz = 0;
    __syncthreads();
    int lim = nwords < 4096 ? nwords : 4096;
    for (int i = threadIdx.x * 2 + 1; i < lim; i += 512)
        if (raw[i] != 0) atomicAdd(&nz, 1);
    __syncthreads();
    if (threadIdx.x == 0) *flag = (nz == 0) ? 1 : 0;   // 1 => int64 storage
}

__global__ void zero2(int* __restrict__ a, int* __restrict__ b, int n) {
    int i = blockIdx.x * blockDim.x + threadIdx.x;
    if (i < n) { a[i] = 0; b[i] = 0; }
}

__global__ void convert_count(const int* __restrict__ raw, int E,
                              const int* __restrict__ flag,
                              int* __restrict__ idx32, int* __restrict__ counts) {
    int i = blockIdx.x * blockDim.x + threadIdx.x;
    if (i >= E) return;
    int f = *flag;
    int s = f ? raw[2 * i] : raw[i];
    int d = f ? raw[2 * (E + i)] : raw[E + i];
    idx32[i] = s;
    idx32[E + i] = d;
    atomicAdd(&counts[d], 1);
}

__global__ void scan_block(const int* __restrict__ counts, int* __restrict__ inc,
                           int* __restrict__ blockSums, int N) {
    __shared__ int sh[256];
    int i = blockIdx.x * 256 + threadIdx.x;
    int v = (i < N) ? counts[i] : 0;
    sh[threadIdx.x] = v;
    __syncthreads();
    for (int off = 1; off < 256; off <<= 1) {
        int t = (threadIdx.x >= off) ? sh[threadIdx.x - off] : 0;
        __syncthreads();
        sh[threadIdx.x] += t;
        __syncthreads();
    }
    if (i < N) inc[i] = sh[threadIdx.x];
    if (threadIdx.x == 255) blockSums[blockIdx.x] = sh[255];
}

__global__ void scan_sums(int* __restrict__ blockSums, int nb, int* __restrict__ row_ptr) {
    __shared__ int sh[512];
    int v = ((int)threadIdx.x < nb) ? blockSums[threadIdx.x] : 0;
    sh[threadIdx.x] = v;
    __syncthreads();
    for (int off = 1; off < 512; off <<= 1) {
        int t = (threadIdx.x >= off) ? sh[threadIdx.x - off] : 0;
        __syncthreads();
        sh[threadIdx.x] += t;
        __syncthreads();
    }
    if ((int)threadIdx.x < nb) blockSums[threadIdx.x] = sh[threadIdx.x];
    if (threadIdx.x == 0) row_ptr[0] = 0;
}

__global__ void scan_add(const int* __restrict__ inc, const int* __restrict__ blockSums,
                         int* __restrict__ row_ptr, int N) {
    int i = blockIdx.x * 256 + threadIdx.x;
    if (i < N) row_ptr[i + 1] = inc[i] + (blockIdx.x > 0 ? blockSums[blockIdx.x - 1] : 0);
}

__global__ void edge_fill(const int* __restrict__ src, const int* __restrict__ dst, int E,
                          const int* __restrict__ row_ptr, int* __restrict__ cursor,
                          int* __restrict__ col) {
    int i = blockIdx.x * blockDim.x + threadIdx.x;
    if (i < E) {
        int d = dst[i];
        int pos = row_ptr[d] + atomicAdd(&cursor[d], 1);
        col[pos] = src[i];
    }
}

// ---------------- conversions ----------------
__global__ void convert_padrow(const float* __restrict__ in, ushort_t* __restrict__ out,
                               int M, int Kr, int Kp) {
    int i = blockIdx.x * blockDim.x + threadIdx.x;
    if (i >= M * Kp) return;
    int r = i / Kp, c = i - r * Kp;
    out[i] = f2bf((c < Kr) ? in[(size_t)r * Kr + c] : 0.f);
}

struct WConv { const float* in; ushort_t* out; int Kp, Kr, N, Npad, blkOff; };
struct WConvArr { WConv e[7]; int n; };

__global__ void convert_w_multi(WConvArr a) {
    int b = blockIdx.x;
    int ei = 0;
    for (int k = 1; k < a.n; k++)
        if (b >= a.e[k].blkOff) ei = k;
    WConv w = a.e[ei];
    int i = (b - w.blkOff) * 256 + threadIdx.x;
    if (i >= w.Npad * w.Kp) return;
    int n = i / w.Kp, k = i - n * w.Kp;
    float v = (n < w.N && k < w.Kr) ? w.in[(size_t)k * w.N + n] : 0.f;
    w.out[i] = f2bf(v);
}

// ---------------- staged GAT GEMM with async LDS DMA (R8) ----------------
__global__ __launch_bounds__(256) void gemm_gat(
    const ushort_t* __restrict__ A, const ushort_t* __restrict__ Bt,
    const float* __restrict__ a_src, const float* __restrict__ a_dst,
    ushort_t* __restrict__ Hbf, float* __restrict__ al_s, float* __restrict__ al_d,
    int M, int K) {
    __shared__ __align__(16) ushort_t As[128 * 32];
    __shared__ __align__(16) ushort_t Bs[128 * 32];
    int t = threadIdx.x;
    int wave = t >> 6, lane = t & 63;
    int wm = (wave >> 1) << 6;
    int wn = (wave & 1) << 6;
    int rowBase = blockIdx.y << 7;
    int colBase = blockIdx.x << 7;
    int lrow = lane & 15, lquad = lane >> 4;
    floatx4 acc[4][4];
#pragma unroll
    for (int i = 0; i < 4; i++)
#pragma unroll
        for (int j = 0; j < 4; j++) acc[i][j] = (floatx4){0.f, 0.f, 0.f, 0.f};

    int c0 = wave * 64 + lane;
    const ushort_t* gA0 = A + (size_t)(rowBase + (c0 >> 2)) * K + ((c0 & 3) << 3);
    const ushort_t* gB0 = Bt + (size_t)(colBase + (c0 >> 2)) * K + ((c0 & 3) << 3);
    int c1 = 256 + c0;
    const ushort_t* gA1 = A + (size_t)(rowBase + (c1 >> 2)) * K + ((c1 & 3) << 3);
    const ushort_t* gB1 = Bt + (size_t)(colBase + (c1 >> 2)) * K + ((c1 & 3) << 3);
    ushort_t* lA0 = As + (size_t)(wave * 64) * 8;
    ushort_t* lB0 = Bs + (size_t)(wave * 64) * 8;
    ushort_t* lA1 = As + (size_t)(256 + wave * 64) * 8;
    ushort_t* lB1 = Bs + (size_t)(256 + wave * 64) * 8;

    for (int k0 = 0; k0 < K; k0 += 32) {
        gl_lds16(gA0 + k0, lA0);
        gl_lds16(gA1 + k0, lA1);
        gl_lds16(gB0 + k0, lB0);
        gl_lds16(gB1 + k0, lB1);
        __syncthreads();
        bf16x8 af[4], bfv[4];
#pragma unroll
        for (int i = 0; i < 4; i++)
            af[i] = *(const bf16x8*)(As + (wm + i * 16 + lrow) * 32 + lquad * 8);
#pragma unroll
        for (int j = 0; j < 4; j++)
            bfv[j] = *(const bf16x8*)(Bs + (wn + j * 16 + lrow) * 32 + lquad * 8);
#pragma unroll
        for (int i = 0; i < 4; i++)
#pragma unroll
            for (int j = 0; j < 4; j++)
                acc[i][j] = __builtin_amdgcn_mfma_f32_16x16x32_bf16(af[i], bfv[j],
                                                                    acc[i][j], 0, 0, 0);
        __syncthreads();
    }
    // epilogue: al_s/al_d per (row, head) + bf16 h store (NCOL=256)
    int head = (colBase + wn) >> 6;
    float avs[4], avd[4];
#pragma unroll
    for (int j = 0; j < 4; j++) {
        avs[j] = a_src[head * 64 + j * 16 + lrow];
        avd[j] = a_dst[head * 64 + j * 16 + lrow];
    }
#pragma unroll
    for (int i = 0; i < 4; i++) {
#pragma unroll
        for (int r = 0; r < 4; r++) {
            float ps = 0.f, pd = 0.f;
#pragma unroll
            for (int j = 0; j < 4; j++) {
                ps += acc[i][j][r] * avs[j];
                pd += acc[i][j][r] * avd[j];
            }
#pragma unroll
            for (int off = 1; off < 16; off <<= 1) {
                ps += __shfl_xor(ps, off);
                pd += __shfl_xor(pd, off);
            }
            if (lrow == 0) {
                int gr = rowBase + wm + i * 16 + lquad * 4 + r;
                al_s[gr * 4 + head] = ps;
                al_d[gr * 4 + head] = pd;
            }
        }
        int grb = rowBase + wm + i * 16 + lquad * 4;
#pragma unroll
        for (int j = 0; j < 4; j++) {
            int gc = colBase + wn + j * 16 + lrow;
#pragma unroll
            for (int r = 0; r < 4; r++)
                Hbf[(size_t)(grb + r) * 256 + gc] = f2bf(acc[i][j][r]);
        }
    }
}

// ---------------- staged bf16 MFMA GEMM (+bias, +lrelu), fp32/bf16 out ------
__global__ __launch_bounds__(256) void gemm_plain(
    const ushort_t* __restrict__ A, const ushort_t* __restrict__ Bt,
    const float* __restrict__ bias, void* __restrict__ Cout,
    int M, int N, int K, int act, float slope, int outBf) {
    __shared__ __align__(16) ushort_t As[128 * 32];
    __shared__ __align__(16) ushort_t Bs[128 * 32];
    int t = threadIdx.x;
    int wave = t >> 6, lane = t & 63;
    int wm = (wave >> 1) << 6;
    int wn = (wave & 1) << 6;
    int rowBase = blockIdx.y << 7;
    int colBase = blockIdx.x << 7;
    int lrow = lane & 15, lquad = lane >> 4;
    floatx4 acc[4][4];
#pragma unroll
    for (int i = 0; i < 4; i++)
#pragma unroll
        for (int j = 0; j < 4; j++) acc[i][j] = (floatx4){0.f, 0.f, 0.f, 0.f};

    int c0 = wave * 64 + lane;
    const ushort_t* gA0 = A + (size_t)(rowBase + (c0 >> 2)) * K + ((c0 & 3) << 3);
    const ushort_t* gB0 = Bt + (size_t)(colBase + (c0 >> 2)) * K + ((c0 & 3) << 3);
    int c1 = 256 + c0;
    const ushort_t* gA1 = A + (size_t)(rowBase + (c1 >> 2)) * K + ((c1 & 3) << 3);
    const ushort_t* gB1 = Bt + (size_t)(colBase + (c1 >> 2)) * K + ((c1 & 3) << 3);
    ushort_t* lA0 = As + (size_t)(wave * 64) * 8;
    ushort_t* lB0 = Bs + (size_t)(wave * 64) * 8;
    ushort_t* lA1 = As + (size_t)(256 + wave * 64) * 8;
    ushort_t* lB1 = Bs + (size_t)(256 + wave * 64) * 8;

    for (int k0 = 0; k0 < K; k0 += 32) {
        gl_lds16(gA0 + k0, lA0);
        gl_lds16(gA1 + k0, lA1);
        gl_lds16(gB0 + k0, lB0);
        gl_lds16(gB1 + k0, lB1);
        __syncthreads();
        bf16x8 af[4], bfv[4];
#pragma unroll
        for (int i = 0; i < 4; i++)
            af[i] = *(const bf16x8*)(As + (wm + i * 16 + lrow) * 32 + lquad * 8);
#pragma unroll
        for (int j = 0; j < 4; j++)
            bfv[j] = *(const bf16x8*)(Bs + (wn + j * 16 + lrow) * 32 + lquad * 8);
#pragma unroll
        for (int i = 0; i < 4; i++)
#pragma unroll
            for (int j = 0; j < 4; j++)
                acc[i][j] = __builtin_amdgcn_mfma_f32_16x16x32_bf16(af[i], bfv[j],
                                                                    acc[i][j], 0, 0, 0);
        __syncthreads();
    }
#pragma unroll
    for (int i = 0; i < 4; i++) {
        int gr = rowBase + wm + i * 16 + lquad * 4;
#pragma unroll
        for (int j = 0; j < 4; j++) {
            int gc = colBase + wn + j * 16 + lrow;
            if (gc >= N) continue;
            float b = bias ? bias[gc] : 0.f;
#pragma unroll
            for (int r = 0; r < 4; r++) {
                float v = acc[i][j][r] + b;
                if (act) v = lrelu(v, slope);
                if (outBf)
                    ((ushort_t*)Cout)[(size_t)(gr + r) * N + gc] = f2bf(v);
                else
                    ((float*)Cout)[(size_t)(gr + r) * N + gc] = v;
            }
        }
    }
}

// ---------------- aggregation: TWO nodes per wave, batch-4 gather ------------
// lanes 0-31 -> node A, 32-63 -> node B; 16B/lane (8 channels, ushort8).
__global__ __launch_bounds__(256) void gat_agg(
    const ushort_t* __restrict__ h_bf, const float* __restrict__ al_s,
    const float* __restrict__ al_d, const int* __restrict__ row_ptr,
    const int* __restrict__ col, const float* __restrict__ bias,
    ushort_t* __restrict__ out_bf, int N, int act, float slope) {
    int wid = (blockIdx.x * 256 + threadIdx.x) >> 6;   // wave index
    int lane = threadIdx.x & 63;
    int half = lane >> 5;
    int lane8 = lane & 31;
    int n = wid * 2 + half;
    if (n >= N) return;
    int head = lane8 >> 3;                 // 8 lanes per head, 8 ch per lane
    int idx4 = n * 4 + head;
    float ad = al_d[idx4];
    const ushort8v* h8 = (const ushort8v*)h_bf;   // row stride 32 ushort8
    // self loop
    float p = __expf(lrelu(al_s[idx4] + ad, GAT_SLOPE));
    ushort8v hv = h8[(size_t)n * 32 + lane8];
    float s = p;
    float acc[8];
#pragma unroll
    for (int c = 0; c < 8; c++) acc[c] = p * bf2f(hv[c]);
    int beg = row_ptr[n], end = row_ptr[n + 1];
    for (int i = beg; i < end; i += 4) {
        int cnt = end - i;
        int sn0 = col[i];
        int sn1 = (cnt > 1) ? col[i + 1] : sn0;
        int sn2 = (cnt > 2) ? col[i + 2] : sn0;
        int sn3 = (cnt > 3) ? col[i + 3] : sn0;
        ushort8v h0 = h8[(size_t)sn0 * 32 + lane8];
        ushort8v h1 = h8[(size_t)sn1 * 32 + lane8];
        ushort8v h2 = h8[(size_t)sn2 * 32 + lane8];
        ushort8v h3 = h8[(size_t)sn3 * 32 + lane8];
        float a0 = al_s[sn0 * 4 + head];
        float a1 = al_s[sn1 * 4 + head];
        float a2 = al_s[sn2 * 4 + head];
        float a3 = al_s[sn3 * 4 + head];
        float p0 = __expf(lrelu(a0 + ad, GAT_SLOPE));
#pragma unroll
        for (int c = 0; c < 8; c++) acc[c] += p0 * bf2f(h0[c]);
        s += p0;
        if (cnt > 1) {
            float p1 = __expf(lrelu(a1 + ad, GAT_SLOPE));
#pragma unroll
            for (int c = 0; c < 8; c++) acc[c] += p1 * bf2f(h1[c]);
            s += p1;
        }
        if (cnt > 2) {
            float p2 = __expf(lrelu(a2 + ad, GAT_SLOPE));
#pragma unroll
            for (int c = 0; c < 8; c++) acc[c] += p2 * bf2f(h2[c]);
            s += p2;
        }
        if (cnt > 3) {
            float p3 = __expf(lrelu(a3 + ad, GAT_SLOPE));
#pragma unroll
            for (int c = 0; c < 8; c++) acc[c] += p3 * bf2f(h3[c]);
            s += p3;
        }
    }
    float rs = 1.f / s;
    const float4* b4 = (const float4*)bias;
    float4 b0 = b4[lane8 * 2];
    float4 b1 = b4[lane8 * 2 + 1];
    float bv[8] = {b0.x, b0.y, b0.z, b0.w, b1.x, b1.y, b1.z, b1.w};
    ushort8v o;
#pragma unroll
    for (int c = 0; c < 8; c++) {
        float v = acc[c] * rs + bv[c];
        if (act) v = lrelu(v, slope);
        o[c] = f2bf(v);
    }
    ((ushort8v*)out_bf)[(size_t)n * 32 + lane8] = o;
}

// ---------------------------------------------------------------------------
extern "C" void kernel_launch(void* const* d_in, const int* in_sizes, int n_in,
                              void* d_out, int out_size, void* d_ws, size_t ws_size,
                              hipStream_t stream) {
    const float* x        = (const float*)d_in[0];
    const int*   rawEdge  = (const int*)d_in[1];
    const float* rootCtx  = (const float*)d_in[2];
    const float* W[3]     = {(const float*)d_in[3], (const float*)d_in[7], (const float*)d_in[11]};
    const float* aS[3]    = {(const float*)d_in[4], (const float*)d_in[8], (const float*)d_in[12]};
    const float* aD[3]    = {(const float*)d_in[5], (const float*)d_in[9], (const float*)d_in[13]};
    const float* bb[3]    = {(const float*)d_in[6], (const float*)d_in[10], (const float*)d_in[14]};
    const float* fc_w     = (const float*)d_in[15];
    const float* fc_b     = (const float*)d_in[16];
    const float* r_w1     = (const float*)d_in[17];
    const float* r_b1     = (const float*)d_in[18];
    const float* r_w2     = (const float*)d_in[19];
    const float* r_b2     = (const float*)d_in[20];
    const float* r_w3     = (const float*)d_in[21];
    const float* r_b3     = (const float*)d_in[22];

    const int N  = in_sizes[0] / 80;      // 102400
    const int E  = in_sizes[1] / 2;       // 409600
    const int R  = in_sizes[2] / 60;      // 4096
    const int N4 = N * 4;

    float* outRot  = (float*)d_out;                  // [N, 80]
    float* outRoot = (float*)d_out + (size_t)N * 80; // [R, 60]

    // ---- carve workspace ----
    size_t off = 0;
    auto carve = [&](size_t bytes) -> void* {
        off = (off + 255) & ~(size_t)255;
        void* p = (char*)d_ws + off;
        off += bytes;
        return p;
    };
    int*      flag      = (int*)carve(4);
    int*      idx32     = (int*)carve((size_t)2 * E * 4);
    int*      counts    = (int*)carve((size_t)N * 4);
    int*      cursor    = (int*)carve((size_t)N * 4);
    int*      row_ptr   = (int*)carve((size_t)(N + 1) * 4);
    int*      incArr    = (int*)carve((size_t)N * 4);
    int*      blockSums = (int*)carve(512 * 4);
    int*      colArr    = (int*)carve((size_t)E * 4);
    float*    al_s      = (float*)carve((size_t)N4 * 4);
    float*    al_d      = (float*)carve((size_t)N4 * 4);
    ushort_t* h_bf      = (ushort_t*)carve((size_t)N * 256 * 2);
    ushort_t* agg_bf    = (ushort_t*)carve((size_t)N * 256 * 2);
    ushort_t* x_bf      = (ushort_t*)carve((size_t)N * 96 * 2);    // Kp=96
    ushort_t* rc_bf     = (ushort_t*)carve((size_t)R * 64 * 2);
    ushort_t* t1_bf     = (ushort_t*)carve((size_t)R * 512 * 2);
    ushort_t* t2_bf     = (ushort_t*)carve((size_t)R * 512 * 2);
    ushort_t* Wt0       = (ushort_t*)carve((size_t)256 * 96 * 2);  // Kp=96
    ushort_t* Wt1       = (ushort_t*)carve((size_t)256 * 256 * 2);
    ushort_t* Wt2       = (ushort_t*)carve((size_t)256 * 256 * 2);
    ushort_t* fcWt      = (ushort_t*)carve((size_t)128 * 256 * 2);
    ushort_t* rW1t      = (ushort_t*)carve((size_t)512 * 64 * 2);
    ushort_t* rWt2      = (ushort_t*)carve((size_t)512 * 512 * 2);
    ushort_t* rWt3      = (ushort_t*)carve((size_t)128 * 512 * 2);

    const int nb = (N + 255) / 256;
    dim3 blk(256);

    // ---- edge format + CSR build ----
    detect_fmt<<<1, 256, 0, stream>>>(rawEdge, 2 * E, flag);
    zero2<<<(N + 255) / 256, blk, 0, stream>>>(counts, cursor, N);
    convert_count<<<(E + 255) / 256, blk, 0, stream>>>(rawEdge, E, flag, idx32, counts);
    const int* srcArr = idx32;
    const int* dstArr = idx32 + E;
    scan_block<<<nb, 256, 0, stream>>>(counts, incArr, blockSums, N);
    scan_sums<<<1, 512, 0, stream>>>(blockSums, nb, row_ptr);
    scan_add<<<nb, 256, 0, stream>>>(incArr, blockSums, row_ptr, N);
    edge_fill<<<(E + 255) / 256, blk, 0, stream>>>(srcArr, dstArr, E, row_ptr, cursor, colArr);

    // ---- weight conversions (merged) ----
    {
        WConvArr wa;
        auto mk = [&](int i, const float* in, ushort_t* out, int Kp, int Kr, int Nn, int Npad,
                      int blkOff) {
            wa.e[i] = WConv{in, out, Kp, Kr, Nn, Npad, blkOff};
        };
        int boff = 0;
        auto nblk = [](int Npad, int Kp) { return (Npad * Kp + 255) / 256; };
        mk(0, W[0], Wt0, 96, 80, 256, 256, boff);   boff += nblk(256, 96);
        mk(1, W[1], Wt1, 256, 256, 256, 256, boff); boff += nblk(256, 256);
        mk(2, W[2], Wt2, 256, 256, 256, 256, boff); boff += nblk(256, 256);
        mk(3, fc_w, fcWt, 256, 256, 80, 128, boff); boff += nblk(128, 256);
        mk(4, r_w1, rW1t, 64, 60, 512, 512, boff);  boff += nblk(512, 64);
        mk(5, r_w2, rWt2, 512, 512, 512, 512, boff); boff += nblk(512, 512);
        mk(6, r_w3, rWt3, 512, 512, 60, 128, boff);  boff += nblk(128, 512);
        wa.n = 7;
        convert_w_multi<<<boff, blk, 0, stream>>>(wa);
    }
    convert_padrow<<<(N * 96 + 255) / 256, blk, 0, stream>>>(x, x_bf, N, 80, 96);
    convert_padrow<<<(R * 64 + 255) / 256, blk, 0, stream>>>(rootCtx, rc_bf, R, 60, 64);

    // ---- GAT layers ----
    const int aggBlocks = (N / 2 + 3) / 4;   // 2 nodes/wave, 4 waves/block
    const ushort_t* curA = x_bf;
    int curK = 96;
    for (int l = 0; l < 3; l++) {
        dim3 g1(2, N / 128);
        gemm_gat<<<g1, blk, 0, stream>>>(curA, l == 0 ? Wt0 : (l == 1 ? Wt1 : Wt2),
                                         aS[l], aD[l], h_bf, al_s, al_d, N, curK);
        int act = (l < 2) ? 1 : 0;
        gat_agg<<<aggBlocks, blk, 0, stream>>>(h_bf, al_s, al_d, row_ptr,
                                               colArr, bb[l], agg_bf, N,
                                               act, ACT_SLOPE);
        curA = agg_bf;
        curK = 256;
    }

    // ---- rot = h @ fc_w + fc_b ----
    {
        dim3 g(1, N / 128);
        gemm_plain<<<g, blk, 0, stream>>>(agg_bf, fcWt, fc_b, outRot, N, 80, 256,
                                          0, 0.f, 0);
    }
    // ---- MLP branch (staged MFMA chain) ----
    {
        dim3 g1(512 / 128, R / 128);
        gemm_plain<<<g1, blk, 0, stream>>>(rc_bf, rW1t, r_b1, t1_bf, R, 512, 64,
                                           1, ACT_SLOPE, 1);
        dim3 g2(512 / 128, R / 128);
        gemm_plain<<<g2, blk, 0, stream>>>(t1_bf, rWt2, r_b2, t2_bf, R, 512, 512,
                                           1, ACT_SLOPE, 1);
        dim3 g3(1, R / 128);
        gemm_plain<<<g3, blk, 0, stream>>>(t2_bf, rWt3, r_b3, outRoot, R, 60, 512,
                                           0, 0.f, 0);
    }
}